// Round 1
// baseline (1105.551 us; speedup 1.0000x reference)
//
#include <hip/hip_runtime.h>

#define Hh 1024
#define Ww 1024
#define PW 1026   // padded width/height (1-px zero halo)

// ---------------------------------------------------------------------------
// prep: per padded pixel -> Ypad (luma, zero halo), bpad (IQ seed, zero halo),
//       mask (isColored), x0 = b, x1 = 0
// ---------------------------------------------------------------------------
__global__ __launch_bounds__(256)
void prep_kernel(const float* __restrict__ gray, const float* __restrict__ app,
                 float* __restrict__ Ypad, float2* __restrict__ bpad,
                 unsigned char* __restrict__ mask,
                 float2* __restrict__ x0, float2* __restrict__ x1) {
    int px = blockIdx.x * blockDim.x + threadIdx.x;
    int py = blockIdx.y * blockDim.y + threadIdx.y;
    if (px >= PW || py >= PW) return;
    int p = py * PW + px;
    float2 bv = make_float2(0.f, 0.f);
    float yv = 0.f;
    if (px >= 1 && px <= Ww && py >= 1 && py <= Hh) {
        int i = py - 1, j = px - 1;
        int idx = i * Ww + j;
        const float s = 1.f / 255.f;
        float gr = gray[idx * 3 + 0] * s;
        float gg = gray[idx * 3 + 1] * s;
        float gb = gray[idx * 3 + 2] * s;
        float ar = app[idx * 3 + 0] * s;
        float ag = app[idx * 3 + 1] * s;
        float ab = app[idx * 3 + 2] * s;
        float diff = fabsf(gr - ar) + fabsf(gg - ag) + fabsf(gb - ab);
        bool colored = diff > 0.01f;
        yv = 0.3f * gr + 0.59f * gg + 0.11f * gb;
        float ay = 0.3f * ar + 0.59f * ag + 0.11f * ab;
        float ai = 0.74f * (ar - ay) - 0.27f * (ab - ay);
        float aq = 0.48f * (ar - ay) + 0.41f * (ab - ay);
        if (colored) bv = make_float2(ai, aq);
        mask[idx] = colored ? 1 : 0;
    }
    Ypad[p] = yv;
    bpad[p] = bv;
    x0[p] = bv;
    x1[p] = make_float2(0.f, 0.f);
}

// ---------------------------------------------------------------------------
// weights: per interior pixel, compute 8 normalized neighbor weights
// (valid-masked, zeroed if pixel is colored). Stored as 2x float4 per pixel.
// ---------------------------------------------------------------------------
__global__ __launch_bounds__(256)
void weights_kernel(const float* __restrict__ Ypad,
                    const unsigned char* __restrict__ mask,
                    float4* __restrict__ w) {
    int j = blockIdx.x * blockDim.x + threadIdx.x;
    int i = blockIdx.y * blockDim.y + threadIdx.y;
    int idx = i * Ww + j;
    int p = (i + 1) * PW + (j + 1);
    float yc = Ypad[p];
    float yn[8];
    yn[0] = Ypad[p - PW - 1]; yn[1] = Ypad[p - PW]; yn[2] = Ypad[p - PW + 1];
    yn[3] = Ypad[p - 1];                            yn[4] = Ypad[p + 1];
    yn[5] = Ypad[p + PW - 1]; yn[6] = Ypad[p + PW]; yn[7] = Ypad[p + PW + 1];
    float vt = (i > 0) ? 1.f : 0.f;
    float vb = (i < Hh - 1) ? 1.f : 0.f;
    float vl = (j > 0) ? 1.f : 0.f;
    float vr = (j < Ww - 1) ? 1.f : 0.f;
    float v[8] = { vt * vl, vt, vt * vr, vl, vr, vb * vl, vb, vb * vr };

    float count = 1.f, s1 = yc;
#pragma unroll
    for (int k = 0; k < 8; ++k) { count += v[k]; s1 += v[k] * yn[k]; }
    float mean = s1 / count;
    float var = (yc - mean) * (yc - mean);
#pragma unroll
    for (int k = 0; k < 8; ++k) { float d = yn[k] - mean; var += v[k] * d * d; }
    var /= count;
    float vs = fmaxf(0.6f * var, 2e-6f);
    float inv_vs = 1.f / vs;

    float wk[8], ws = 0.f;
#pragma unroll
    for (int k = 0; k < 8; ++k) {
        float d = yn[k] - yc;
        wk[k] = v[k] * expf(-d * d * inv_vs);
        ws += wk[k];
    }
    float scale = mask[idx] ? 0.f : (1.f / ws);
    w[2 * idx + 0] = make_float4(wk[0] * scale, wk[1] * scale, wk[2] * scale, wk[3] * scale);
    w[2 * idx + 1] = make_float4(wk[4] * scale, wk[5] * scale, wk[6] * scale, wk[7] * scale);
}

// ---------------------------------------------------------------------------
// iter: x_new = b + sum_k w_k * x_nbr_k   (2 channels), padded in/out
// ---------------------------------------------------------------------------
__global__ __launch_bounds__(256)
void iter_kernel(const float2* __restrict__ xin, float2* __restrict__ xout,
                 const float4* __restrict__ w, const float2* __restrict__ bpad) {
    int j = blockIdx.x * blockDim.x + threadIdx.x;
    int i = blockIdx.y * blockDim.y + threadIdx.y;
    int idx = i * Ww + j;
    int p = (i + 1) * PW + (j + 1);

    float4 w0 = w[2 * idx + 0];
    float4 w1 = w[2 * idx + 1];
    float2 acc = bpad[p];

    float2 n0 = xin[p - PW - 1];
    float2 n1 = xin[p - PW];
    float2 n2 = xin[p - PW + 1];
    float2 n3 = xin[p - 1];
    float2 n4 = xin[p + 1];
    float2 n5 = xin[p + PW - 1];
    float2 n6 = xin[p + PW];
    float2 n7 = xin[p + PW + 1];

    acc.x = fmaf(w0.x, n0.x, acc.x); acc.y = fmaf(w0.x, n0.y, acc.y);
    acc.x = fmaf(w0.y, n1.x, acc.x); acc.y = fmaf(w0.y, n1.y, acc.y);
    acc.x = fmaf(w0.z, n2.x, acc.x); acc.y = fmaf(w0.z, n2.y, acc.y);
    acc.x = fmaf(w0.w, n3.x, acc.x); acc.y = fmaf(w0.w, n3.y, acc.y);
    acc.x = fmaf(w1.x, n4.x, acc.x); acc.y = fmaf(w1.x, n4.y, acc.y);
    acc.x = fmaf(w1.y, n5.x, acc.x); acc.y = fmaf(w1.y, n5.y, acc.y);
    acc.x = fmaf(w1.z, n6.x, acc.x); acc.y = fmaf(w1.z, n6.y, acc.y);
    acc.x = fmaf(w1.w, n7.x, acc.x); acc.y = fmaf(w1.w, n7.y, acc.y);

    xout[p] = acc;
}

// ---------------------------------------------------------------------------
// final: yiq -> rgb, clip, *255
// ---------------------------------------------------------------------------
__global__ __launch_bounds__(256)
void final_kernel(const float* __restrict__ Ypad, const float2* __restrict__ x,
                  float* __restrict__ out) {
    int j = blockIdx.x * blockDim.x + threadIdx.x;
    int i = blockIdx.y * blockDim.y + threadIdx.y;
    int idx = i * Ww + j;
    int p = (i + 1) * PW + (j + 1);
    float y = Ypad[p];
    float2 iq = x[p];
    float R = y + 0.9468822170900693f * iq.x + 0.6235565819861433f * iq.y;
    float G = y - 0.27478764629897834f * iq.x - 0.6356910791873801f * iq.y;
    float B = y - 1.1085450346420322f * iq.x + 1.7090069284064666f * iq.y;
    out[idx * 3 + 0] = fminf(fmaxf(R, 0.f), 1.f) * 255.f;
    out[idx * 3 + 1] = fminf(fmaxf(G, 0.f), 1.f) * 255.f;
    out[idx * 3 + 2] = fminf(fmaxf(B, 0.f), 1.f) * 255.f;
}

extern "C" void kernel_launch(void* const* d_in, const int* in_sizes, int n_in,
                              void* d_out, int out_size, void* d_ws, size_t ws_size,
                              hipStream_t stream) {
    const float* gray = (const float*)d_in[0];
    const float* app  = (const float*)d_in[1];
    float* out = (float*)d_out;

    char* ws = (char*)d_ws;
    size_t off = 0;
    auto alloc = [&](size_t bytes) -> void* {
        void* r = ws + off;
        off = (off + bytes + 255) & ~(size_t)255;
        return r;
    };
    float*  Ypad = (float*) alloc((size_t)PW * PW * sizeof(float));
    float4* w    = (float4*)alloc((size_t)Hh * Ww * 8 * sizeof(float));
    float2* bpad = (float2*)alloc((size_t)PW * PW * sizeof(float2));
    unsigned char* mask = (unsigned char*)alloc((size_t)Hh * Ww);
    float2* x0   = (float2*)alloc((size_t)PW * PW * sizeof(float2));
    float2* x1   = (float2*)alloc((size_t)PW * PW * sizeof(float2));

    dim3 blk(64, 4);
    dim3 gridPad((PW + 63) / 64, (PW + 3) / 4);
    prep_kernel<<<gridPad, blk, 0, stream>>>(gray, app, Ypad, bpad, mask, x0, x1);

    dim3 grid(Ww / 64, Hh / 4);
    weights_kernel<<<grid, blk, 0, stream>>>(Ypad, mask, w);

    float2* xin = x0;
    float2* xout = x1;
    for (int t = 0; t < 100; ++t) {
        iter_kernel<<<grid, blk, 0, stream>>>(xin, xout, w, bpad);
        float2* tmp = xin; xin = xout; xout = tmp;
    }
    final_kernel<<<grid, blk, 0, stream>>>(Ypad, xin, out);
}

// Round 2
// 698.936 us; speedup vs baseline: 1.5818x; 1.5818x over previous
//
#include <hip/hip_runtime.h>

#define Hh 1024
#define Ww 1024
#define PS 1040      // padded row stride (image at offset PO)
#define PO 8         // halo offset (>= T+1)
#define T 5          // fused iterations per launch (100 = 20 launches x 5)
#define TILE 32      // output tile per block
#define R 42         // region = TILE + 2T
#define XS 43        // LDS row stride in float2 (R+1, avoids pow2 patterns)
#define NPX (R * R)  // 1764 region pixels

// ---------------------------------------------------------------------------
// prep: Ypad (luma, zero halo), x0 = b (IQ if colored else 0, zero halo),
//       x1 = 0 (halo must be zero; interior overwritten), mask (isColored)
// ---------------------------------------------------------------------------
__global__ __launch_bounds__(256)
void prep_kernel(const float* __restrict__ gray, const float* __restrict__ app,
                 float* __restrict__ Ypad, float2* __restrict__ x0,
                 float2* __restrict__ x1, unsigned char* __restrict__ mask) {
    int px = blockIdx.x * 64 + threadIdx.x;
    int py = blockIdx.y * 4 + threadIdx.y;
    if (px >= PS || py >= PS) return;
    int p = py * PS + px;
    int i = py - PO, j = px - PO;
    float yv = 0.f;
    float2 bv = make_float2(0.f, 0.f);
    if (i >= 0 && i < Hh && j >= 0 && j < Ww) {
        int idx = i * Ww + j;
        const float s = 1.f / 255.f;
        float gr = gray[idx * 3 + 0] * s;
        float gg = gray[idx * 3 + 1] * s;
        float gb = gray[idx * 3 + 2] * s;
        float ar = app[idx * 3 + 0] * s;
        float ag = app[idx * 3 + 1] * s;
        float ab = app[idx * 3 + 2] * s;
        float diff = fabsf(gr - ar) + fabsf(gg - ag) + fabsf(gb - ab);
        bool colored = diff > 0.01f;
        yv = 0.3f * gr + 0.59f * gg + 0.11f * gb;
        float ay = 0.3f * ar + 0.59f * ag + 0.11f * ab;
        float ai = 0.74f * (ar - ay) - 0.27f * (ab - ay);
        float aq = 0.48f * (ar - ay) + 0.41f * (ab - ay);
        if (colored) bv = make_float2(ai, aq);
        mask[idx] = colored ? 1 : 0;
    }
    Ypad[p] = yv;
    x0[p] = bv;
    x1[p] = make_float2(0.f, 0.f);
}

// ---------------------------------------------------------------------------
// weights: per padded pixel, 8 normalized neighbor weights (fp32, 2x float4).
// Outside the image: all zero (=> x stays 0 there).
// Colored pixel: all zero, w[0] = -0.0f (sign bit = "keep center").
// ---------------------------------------------------------------------------
__global__ __launch_bounds__(256)
void weights_kernel(const float* __restrict__ Ypad,
                    const unsigned char* __restrict__ mask,
                    float4* __restrict__ w) {
    int px = blockIdx.x * 64 + threadIdx.x;
    int py = blockIdx.y * 4 + threadIdx.y;
    if (px >= PS || py >= PS) return;
    int p = py * PS + px;
    int i = py - PO, j = px - PO;
    float4 lo = make_float4(0.f, 0.f, 0.f, 0.f);
    float4 hi = make_float4(0.f, 0.f, 0.f, 0.f);
    if (i >= 0 && i < Hh && j >= 0 && j < Ww) {
        float yc = Ypad[p];
        float yn[8];
        yn[0] = Ypad[p - PS - 1]; yn[1] = Ypad[p - PS]; yn[2] = Ypad[p - PS + 1];
        yn[3] = Ypad[p - 1];                            yn[4] = Ypad[p + 1];
        yn[5] = Ypad[p + PS - 1]; yn[6] = Ypad[p + PS]; yn[7] = Ypad[p + PS + 1];
        float vt = (i > 0) ? 1.f : 0.f;
        float vb = (i < Hh - 1) ? 1.f : 0.f;
        float vl = (j > 0) ? 1.f : 0.f;
        float vr = (j < Ww - 1) ? 1.f : 0.f;
        float v[8] = { vt * vl, vt, vt * vr, vl, vr, vb * vl, vb, vb * vr };

        float count = 1.f, s1 = yc;
#pragma unroll
        for (int k = 0; k < 8; ++k) { count += v[k]; s1 += v[k] * yn[k]; }
        float mean = s1 / count;
        float var = (yc - mean) * (yc - mean);
#pragma unroll
        for (int k = 0; k < 8; ++k) { float d = yn[k] - mean; var += v[k] * d * d; }
        var /= count;
        float vs = fmaxf(0.6f * var, 2e-6f);
        float inv_vs = 1.f / vs;

        float wk[8], ws = 0.f;
#pragma unroll
        for (int k = 0; k < 8; ++k) {
            float d = yn[k] - yc;
            wk[k] = v[k] * expf(-d * d * inv_vs);
            ws += wk[k];
        }
        if (mask[i * Ww + j]) {
            lo.x = -0.0f;  // sign bit => x_new = x_center (colored pixel frozen)
        } else {
            float scale = 1.f / ws;
            lo = make_float4(wk[0] * scale, wk[1] * scale, wk[2] * scale, wk[3] * scale);
            hi = make_float4(wk[4] * scale, wk[5] * scale, wk[6] * scale, wk[7] * scale);
        }
    }
    w[2 * p + 0] = lo;
    w[2 * p + 1] = hi;
}

// ---------------------------------------------------------------------------
// iter5: temporal-tiled stencil. Loads a 42x42 x-region into LDS, runs 5
// Jacobi sweeps (trapezoid: active region shrinks by 1/side per sweep),
// writes the central 32x32 tile. Weights re-read from global (L1/L2-served).
// ---------------------------------------------------------------------------
__global__ __launch_bounds__(256)
void iter5_kernel(const float2* __restrict__ xin, float2* __restrict__ xout,
                  const float4* __restrict__ w) {
    __shared__ float2 xs[2][R * XS];
    int tid = threadIdx.x;
    int gi0 = blockIdx.y * TILE - T;  // image row of region r=0
    int gj0 = blockIdx.x * TILE - T;

    int rk[7], ck[7];
#pragma unroll
    for (int k = 0; k < 7; ++k) {
        int pidx = tid + k * 256;
        if (pidx < NPX) {
            int r = pidx / R, c = pidx - r * R;
            rk[k] = r; ck[k] = c;
            int gp = (gi0 + r + PO) * PS + (gj0 + c + PO);
            xs[0][r * XS + c] = xin[gp];
        }
    }
    __syncthreads();

    int cur = 0;
#pragma unroll
    for (int t = 1; t <= T; ++t) {
        int nxt = cur ^ 1;
#pragma unroll
        for (int k = 0; k < 7; ++k) {
            int pidx = tid + k * 256;
            if (pidx < NPX) {
                int r = rk[k], c = ck[k];
                if (r >= t && r < R - t && c >= t && c < R - t) {
                    int lp = r * XS + c;
                    int gp = (gi0 + r + PO) * PS + (gj0 + c + PO);
                    float4 w0 = w[2 * gp + 0];
                    float4 w1 = w[2 * gp + 1];
                    float2 ctr = xs[cur][lp];
                    float2 n0 = xs[cur][lp - XS - 1];
                    float2 n1 = xs[cur][lp - XS];
                    float2 n2 = xs[cur][lp - XS + 1];
                    float2 n3 = xs[cur][lp - 1];
                    float2 n4 = xs[cur][lp + 1];
                    float2 n5 = xs[cur][lp + XS - 1];
                    float2 n6 = xs[cur][lp + XS];
                    float2 n7 = xs[cur][lp + XS + 1];
                    bool keep = (__float_as_uint(w0.x) >> 31) != 0u;
                    float2 acc = keep ? ctr : make_float2(0.f, 0.f);
                    acc.x = fmaf(w0.x, n0.x, acc.x); acc.y = fmaf(w0.x, n0.y, acc.y);
                    acc.x = fmaf(w0.y, n1.x, acc.x); acc.y = fmaf(w0.y, n1.y, acc.y);
                    acc.x = fmaf(w0.z, n2.x, acc.x); acc.y = fmaf(w0.z, n2.y, acc.y);
                    acc.x = fmaf(w0.w, n3.x, acc.x); acc.y = fmaf(w0.w, n3.y, acc.y);
                    acc.x = fmaf(w1.x, n4.x, acc.x); acc.y = fmaf(w1.x, n4.y, acc.y);
                    acc.x = fmaf(w1.y, n5.x, acc.x); acc.y = fmaf(w1.y, n5.y, acc.y);
                    acc.x = fmaf(w1.z, n6.x, acc.x); acc.y = fmaf(w1.z, n6.y, acc.y);
                    acc.x = fmaf(w1.w, n7.x, acc.x); acc.y = fmaf(w1.w, n7.y, acc.y);
                    xs[nxt][lp] = acc;
                }
            }
        }
        __syncthreads();
        cur = nxt;
    }

    // write central 32x32 tile
#pragma unroll
    for (int k = 0; k < 4; ++k) {
        int pidx = tid + k * 256;
        int r = T + (pidx >> 5), c = T + (pidx & 31);
        int gp = (gi0 + r + PO) * PS + (gj0 + c + PO);
        xout[gp] = xs[cur][r * XS + c];
    }
}

// ---------------------------------------------------------------------------
// final: yiq -> rgb, clip, *255
// ---------------------------------------------------------------------------
__global__ __launch_bounds__(256)
void final_kernel(const float* __restrict__ Ypad, const float2* __restrict__ x,
                  float* __restrict__ out) {
    int j = blockIdx.x * 64 + threadIdx.x;
    int i = blockIdx.y * 4 + threadIdx.y;
    int idx = i * Ww + j;
    int p = (i + PO) * PS + (j + PO);
    float y = Ypad[p];
    float2 iq = x[p];
    float R_ = y + 0.9468822170900693f * iq.x + 0.6235565819861433f * iq.y;
    float G_ = y - 0.27478764629897834f * iq.x - 0.6356910791873801f * iq.y;
    float B_ = y - 1.1085450346420322f * iq.x + 1.7090069284064666f * iq.y;
    out[idx * 3 + 0] = fminf(fmaxf(R_, 0.f), 1.f) * 255.f;
    out[idx * 3 + 1] = fminf(fmaxf(G_, 0.f), 1.f) * 255.f;
    out[idx * 3 + 2] = fminf(fmaxf(B_, 0.f), 1.f) * 255.f;
}

extern "C" void kernel_launch(void* const* d_in, const int* in_sizes, int n_in,
                              void* d_out, int out_size, void* d_ws, size_t ws_size,
                              hipStream_t stream) {
    const float* gray = (const float*)d_in[0];
    const float* app  = (const float*)d_in[1];
    float* out = (float*)d_out;

    char* ws = (char*)d_ws;
    size_t off = 0;
    auto alloc = [&](size_t bytes) -> void* {
        void* r = ws + off;
        off = (off + bytes + 255) & ~(size_t)255;
        return r;
    };
    float*  Ypad = (float*) alloc((size_t)PS * PS * sizeof(float));
    float4* w    = (float4*)alloc((size_t)PS * PS * 8 * sizeof(float));
    unsigned char* mask = (unsigned char*)alloc((size_t)Hh * Ww);
    float2* x0   = (float2*)alloc((size_t)PS * PS * sizeof(float2));
    float2* x1   = (float2*)alloc((size_t)PS * PS * sizeof(float2));

    dim3 blk(64, 4);
    dim3 gridPad((PS + 63) / 64, (PS + 3) / 4);
    prep_kernel<<<gridPad, blk, 0, stream>>>(gray, app, Ypad, x0, x1, mask);
    weights_kernel<<<gridPad, blk, 0, stream>>>(Ypad, mask, w);

    dim3 gridIter(Ww / TILE, Hh / TILE);  // 32 x 32 blocks
    float2* xin = x0;
    float2* xout = x1;
    for (int l = 0; l < 20; ++l) {        // 20 x 5 = 100 iterations
        iter5_kernel<<<gridIter, 256, 0, stream>>>(xin, xout, w);
        float2* tmp = xin; xin = xout; xout = tmp;
    }

    dim3 gridImg(Ww / 64, Hh / 4);
    final_kernel<<<gridImg, blk, 0, stream>>>(Ypad, xin, out);
}

// Round 3
// 548.535 us; speedup vs baseline: 2.0155x; 1.2742x over previous
//
#include <hip/hip_runtime.h>

#define Hh 1024
#define Ww 1024
#define PS 1040      // padded row stride (image at offset PO)
#define PO 8         // halo offset (>= T+1)
#define T 5          // fused iterations per launch (100 = 20 launches x 5)
#define TILE 32      // output tile per block
#define R 42         // region = TILE + 2T
#define XS 43        // LDS row stride in float2 (R+1, avoids pow2 patterns)
#define NPX (R * R)  // 1764 region pixels
#define NK 7         // ceil(NPX / 256)

// ---------------------------------------------------------------------------
// prep: Ypad (luma, zero halo), x0 = b (IQ if colored else 0, zero halo),
//       x1 = 0 (halo must be zero; interior overwritten), mask (isColored)
// ---------------------------------------------------------------------------
__global__ __launch_bounds__(256)
void prep_kernel(const float* __restrict__ gray, const float* __restrict__ app,
                 float* __restrict__ Ypad, float2* __restrict__ x0,
                 float2* __restrict__ x1, unsigned char* __restrict__ mask) {
    int px = blockIdx.x * 64 + threadIdx.x;
    int py = blockIdx.y * 4 + threadIdx.y;
    if (px >= PS || py >= PS) return;
    int p = py * PS + px;
    int i = py - PO, j = px - PO;
    float yv = 0.f;
    float2 bv = make_float2(0.f, 0.f);
    if (i >= 0 && i < Hh && j >= 0 && j < Ww) {
        int idx = i * Ww + j;
        const float s = 1.f / 255.f;
        float gr = gray[idx * 3 + 0] * s;
        float gg = gray[idx * 3 + 1] * s;
        float gb = gray[idx * 3 + 2] * s;
        float ar = app[idx * 3 + 0] * s;
        float ag = app[idx * 3 + 1] * s;
        float ab = app[idx * 3 + 2] * s;
        float diff = fabsf(gr - ar) + fabsf(gg - ag) + fabsf(gb - ab);
        bool colored = diff > 0.01f;
        yv = 0.3f * gr + 0.59f * gg + 0.11f * gb;
        float ay = 0.3f * ar + 0.59f * ag + 0.11f * ab;
        float ai = 0.74f * (ar - ay) - 0.27f * (ab - ay);
        float aq = 0.48f * (ar - ay) + 0.41f * (ab - ay);
        if (colored) bv = make_float2(ai, aq);
        mask[idx] = colored ? 1 : 0;
    }
    Ypad[p] = yv;
    x0[p] = bv;
    x1[p] = make_float2(0.f, 0.f);
}

// ---------------------------------------------------------------------------
// weights: per padded pixel, 8 normalized neighbor weights (fp32, 2x float4).
// Outside the image: all zero (=> x stays 0 there).
// Colored pixel: all zero, w[0] = -0.0f (sign bit = "keep center").
// ---------------------------------------------------------------------------
__global__ __launch_bounds__(256)
void weights_kernel(const float* __restrict__ Ypad,
                    const unsigned char* __restrict__ mask,
                    float4* __restrict__ w) {
    int px = blockIdx.x * 64 + threadIdx.x;
    int py = blockIdx.y * 4 + threadIdx.y;
    if (px >= PS || py >= PS) return;
    int p = py * PS + px;
    int i = py - PO, j = px - PO;
    float4 lo = make_float4(0.f, 0.f, 0.f, 0.f);
    float4 hi = make_float4(0.f, 0.f, 0.f, 0.f);
    if (i >= 0 && i < Hh && j >= 0 && j < Ww) {
        float yc = Ypad[p];
        float yn[8];
        yn[0] = Ypad[p - PS - 1]; yn[1] = Ypad[p - PS]; yn[2] = Ypad[p - PS + 1];
        yn[3] = Ypad[p - 1];                            yn[4] = Ypad[p + 1];
        yn[5] = Ypad[p + PS - 1]; yn[6] = Ypad[p + PS]; yn[7] = Ypad[p + PS + 1];
        float vt = (i > 0) ? 1.f : 0.f;
        float vb = (i < Hh - 1) ? 1.f : 0.f;
        float vl = (j > 0) ? 1.f : 0.f;
        float vr = (j < Ww - 1) ? 1.f : 0.f;
        float v[8] = { vt * vl, vt, vt * vr, vl, vr, vb * vl, vb, vb * vr };

        float count = 1.f, s1 = yc;
#pragma unroll
        for (int k = 0; k < 8; ++k) { count += v[k]; s1 += v[k] * yn[k]; }
        float mean = s1 / count;
        float var = (yc - mean) * (yc - mean);
#pragma unroll
        for (int k = 0; k < 8; ++k) { float d = yn[k] - mean; var += v[k] * d * d; }
        var /= count;
        float vs = fmaxf(0.6f * var, 2e-6f);
        float inv_vs = 1.f / vs;

        float wk[8], ws = 0.f;
#pragma unroll
        for (int k = 0; k < 8; ++k) {
            float d = yn[k] - yc;
            wk[k] = v[k] * expf(-d * d * inv_vs);
            ws += wk[k];
        }
        if (mask[i * Ww + j]) {
            lo.x = -0.0f;  // sign bit => x_new = x_center (colored pixel frozen)
        } else {
            float scale = 1.f / ws;
            lo = make_float4(wk[0] * scale, wk[1] * scale, wk[2] * scale, wk[3] * scale);
            hi = make_float4(wk[4] * scale, wk[5] * scale, wk[6] * scale, wk[7] * scale);
        }
    }
    w[2 * p + 0] = lo;
    w[2 * p + 1] = hi;
}

// ---------------------------------------------------------------------------
// iter5: temporal-tiled stencil. Loads a 42x42 x-region into LDS AND each
// thread's per-pixel weights into REGISTERS (read once, reused all 5 sweeps
// -- kills the dominant redundant L3 stream). 5 trapezoid Jacobi sweeps in
// LDS ping-pong, writes the central 32x32 tile.
// ---------------------------------------------------------------------------
__global__ __launch_bounds__(256)
void iter5_kernel(const float2* __restrict__ xin, float2* __restrict__ xout,
                  const float4* __restrict__ w) {
    __shared__ float2 xs[2][R * XS];
    int tid = threadIdx.x;
    int gi0 = blockIdx.y * TILE - T;  // image row of region r=0
    int gj0 = blockIdx.x * TILE - T;

    int rk[NK], ck[NK];
    float4 w0r[NK], w1r[NK];
#pragma unroll
    for (int k = 0; k < NK; ++k) {
        int pidx = tid + k * 256;
        if (pidx < NPX) {
            int r = pidx / R, c = pidx - r * R;
            rk[k] = r; ck[k] = c;
            int gp = (gi0 + r + PO) * PS + (gj0 + c + PO);
            xs[0][r * XS + c] = xin[gp];
            w0r[k] = w[2 * gp + 0];
            w1r[k] = w[2 * gp + 1];
        }
    }
    __syncthreads();

    int cur = 0;
#pragma unroll
    for (int t = 1; t <= T; ++t) {
        int nxt = cur ^ 1;
#pragma unroll
        for (int k = 0; k < NK; ++k) {
            int pidx = tid + k * 256;
            if (pidx < NPX) {
                int r = rk[k], c = ck[k];
                if (r >= t && r < R - t && c >= t && c < R - t) {
                    int lp = r * XS + c;
                    float4 w0 = w0r[k];
                    float4 w1 = w1r[k];
                    float2 ctr = xs[cur][lp];
                    float2 n0 = xs[cur][lp - XS - 1];
                    float2 n1 = xs[cur][lp - XS];
                    float2 n2 = xs[cur][lp - XS + 1];
                    float2 n3 = xs[cur][lp - 1];
                    float2 n4 = xs[cur][lp + 1];
                    float2 n5 = xs[cur][lp + XS - 1];
                    float2 n6 = xs[cur][lp + XS];
                    float2 n7 = xs[cur][lp + XS + 1];
                    bool keep = (__float_as_uint(w0.x) >> 31) != 0u;
                    float2 acc = keep ? ctr : make_float2(0.f, 0.f);
                    acc.x = fmaf(w0.x, n0.x, acc.x); acc.y = fmaf(w0.x, n0.y, acc.y);
                    acc.x = fmaf(w0.y, n1.x, acc.x); acc.y = fmaf(w0.y, n1.y, acc.y);
                    acc.x = fmaf(w0.z, n2.x, acc.x); acc.y = fmaf(w0.z, n2.y, acc.y);
                    acc.x = fmaf(w0.w, n3.x, acc.x); acc.y = fmaf(w0.w, n3.y, acc.y);
                    acc.x = fmaf(w1.x, n4.x, acc.x); acc.y = fmaf(w1.x, n4.y, acc.y);
                    acc.x = fmaf(w1.y, n5.x, acc.x); acc.y = fmaf(w1.y, n5.y, acc.y);
                    acc.x = fmaf(w1.z, n6.x, acc.x); acc.y = fmaf(w1.z, n6.y, acc.y);
                    acc.x = fmaf(w1.w, n7.x, acc.x); acc.y = fmaf(w1.w, n7.y, acc.y);
                    xs[nxt][lp] = acc;
                }
            }
        }
        __syncthreads();
        cur = nxt;
    }

    // write central 32x32 tile
#pragma unroll
    for (int k = 0; k < 4; ++k) {
        int pidx = tid + k * 256;
        int r = T + (pidx >> 5), c = T + (pidx & 31);
        int gp = (gi0 + r + PO) * PS + (gj0 + c + PO);
        xout[gp] = xs[cur][r * XS + c];
    }
}

// ---------------------------------------------------------------------------
// final: yiq -> rgb, clip, *255
// ---------------------------------------------------------------------------
__global__ __launch_bounds__(256)
void final_kernel(const float* __restrict__ Ypad, const float2* __restrict__ x,
                  float* __restrict__ out) {
    int j = blockIdx.x * 64 + threadIdx.x;
    int i = blockIdx.y * 4 + threadIdx.y;
    int idx = i * Ww + j;
    int p = (i + PO) * PS + (j + PO);
    float y = Ypad[p];
    float2 iq = x[p];
    float R_ = y + 0.9468822170900693f * iq.x + 0.6235565819861433f * iq.y;
    float G_ = y - 0.27478764629897834f * iq.x - 0.6356910791873801f * iq.y;
    float B_ = y - 1.1085450346420322f * iq.x + 1.7090069284064666f * iq.y;
    out[idx * 3 + 0] = fminf(fmaxf(R_, 0.f), 1.f) * 255.f;
    out[idx * 3 + 1] = fminf(fmaxf(G_, 0.f), 1.f) * 255.f;
    out[idx * 3 + 2] = fminf(fmaxf(B_, 0.f), 1.f) * 255.f;
}

extern "C" void kernel_launch(void* const* d_in, const int* in_sizes, int n_in,
                              void* d_out, int out_size, void* d_ws, size_t ws_size,
                              hipStream_t stream) {
    const float* gray = (const float*)d_in[0];
    const float* app  = (const float*)d_in[1];
    float* out = (float*)d_out;

    char* ws = (char*)d_ws;
    size_t off = 0;
    auto alloc = [&](size_t bytes) -> void* {
        void* r = ws + off;
        off = (off + bytes + 255) & ~(size_t)255;
        return r;
    };
    float*  Ypad = (float*) alloc((size_t)PS * PS * sizeof(float));
    float4* w    = (float4*)alloc((size_t)PS * PS * 8 * sizeof(float));
    unsigned char* mask = (unsigned char*)alloc((size_t)Hh * Ww);
    float2* x0   = (float2*)alloc((size_t)PS * PS * sizeof(float2));
    float2* x1   = (float2*)alloc((size_t)PS * PS * sizeof(float2));

    dim3 blk(64, 4);
    dim3 gridPad((PS + 63) / 64, (PS + 3) / 4);
    prep_kernel<<<gridPad, blk, 0, stream>>>(gray, app, Ypad, x0, x1, mask);
    weights_kernel<<<gridPad, blk, 0, stream>>>(Ypad, mask, w);

    dim3 gridIter(Ww / TILE, Hh / TILE);  // 32 x 32 blocks
    float2* xin = x0;
    float2* xout = x1;
    for (int l = 0; l < 20; ++l) {        // 20 x 5 = 100 iterations
        iter5_kernel<<<gridIter, 256, 0, stream>>>(xin, xout, w);
        float2* tmp = xin; xin = xout; xout = tmp;
    }

    dim3 gridImg(Ww / 64, Hh / 4);
    final_kernel<<<gridImg, blk, 0, stream>>>(Ypad, xin, out);
}

// Round 4
// 375.417 us; speedup vs baseline: 2.9449x; 1.4611x over previous
//
#include <hip/hip_runtime.h>

#define Hh 1024
#define Ww 1024
#define PS 1040      // padded row stride (image at offset PO)
#define PO 8         // halo offset (>= T+1)
#define T 5          // fused iterations per launch (100 = 20 launches x 5)
#define TILE 32      // output tile per block
#define R 42         // region = TILE + 2T
#define XS 44        // LDS row stride in float2 (EVEN -> 16B-aligned float4 reads)
#define NPX (R * R)  // 1764 region pixels
#define NK 7         // ceil(NPX / 256)

// ---------------------------------------------------------------------------
// prep: Ypad (luma, zero halo), x0 = b (IQ if colored else 0, zero halo),
//       x1 = 0, mask (isColored)
// ---------------------------------------------------------------------------
__global__ __launch_bounds__(256)
void prep_kernel(const float* __restrict__ gray, const float* __restrict__ app,
                 float* __restrict__ Ypad, float2* __restrict__ x0,
                 float2* __restrict__ x1, unsigned char* __restrict__ mask) {
    int px = blockIdx.x * 64 + threadIdx.x;
    int py = blockIdx.y * 4 + threadIdx.y;
    if (px >= PS || py >= PS) return;
    int p = py * PS + px;
    int i = py - PO, j = px - PO;
    float yv = 0.f;
    float2 bv = make_float2(0.f, 0.f);
    if (i >= 0 && i < Hh && j >= 0 && j < Ww) {
        int idx = i * Ww + j;
        const float s = 1.f / 255.f;
        float gr = gray[idx * 3 + 0] * s;
        float gg = gray[idx * 3 + 1] * s;
        float gb = gray[idx * 3 + 2] * s;
        float ar = app[idx * 3 + 0] * s;
        float ag = app[idx * 3 + 1] * s;
        float ab = app[idx * 3 + 2] * s;
        float diff = fabsf(gr - ar) + fabsf(gg - ag) + fabsf(gb - ab);
        bool colored = diff > 0.01f;
        yv = 0.3f * gr + 0.59f * gg + 0.11f * gb;
        float ay = 0.3f * ar + 0.59f * ag + 0.11f * ab;
        float ai = 0.74f * (ar - ay) - 0.27f * (ab - ay);
        float aq = 0.48f * (ar - ay) + 0.41f * (ab - ay);
        if (colored) bv = make_float2(ai, aq);
        mask[idx] = colored ? 1 : 0;
    }
    Ypad[p] = yv;
    x0[p] = bv;
    x1[p] = make_float2(0.f, 0.f);
}

// ---------------------------------------------------------------------------
// weights: per padded pixel, 8 normalized neighbor weights (fp32, 2x float4).
// Outside the image: all zero. Colored pixel: all zero, w[0] = -0.0f
// (sign bit = "keep center").
// ---------------------------------------------------------------------------
__global__ __launch_bounds__(256)
void weights_kernel(const float* __restrict__ Ypad,
                    const unsigned char* __restrict__ mask,
                    float4* __restrict__ w) {
    int px = blockIdx.x * 64 + threadIdx.x;
    int py = blockIdx.y * 4 + threadIdx.y;
    if (px >= PS || py >= PS) return;
    int p = py * PS + px;
    int i = py - PO, j = px - PO;
    float4 lo = make_float4(0.f, 0.f, 0.f, 0.f);
    float4 hi = make_float4(0.f, 0.f, 0.f, 0.f);
    if (i >= 0 && i < Hh && j >= 0 && j < Ww) {
        float yc = Ypad[p];
        float yn[8];
        yn[0] = Ypad[p - PS - 1]; yn[1] = Ypad[p - PS]; yn[2] = Ypad[p - PS + 1];
        yn[3] = Ypad[p - 1];                            yn[4] = Ypad[p + 1];
        yn[5] = Ypad[p + PS - 1]; yn[6] = Ypad[p + PS]; yn[7] = Ypad[p + PS + 1];
        float vt = (i > 0) ? 1.f : 0.f;
        float vb = (i < Hh - 1) ? 1.f : 0.f;
        float vl = (j > 0) ? 1.f : 0.f;
        float vr = (j < Ww - 1) ? 1.f : 0.f;
        float v[8] = { vt * vl, vt, vt * vr, vl, vr, vb * vl, vb, vb * vr };

        float count = 1.f, s1 = yc;
#pragma unroll
        for (int k = 0; k < 8; ++k) { count += v[k]; s1 += v[k] * yn[k]; }
        float mean = s1 / count;
        float var = (yc - mean) * (yc - mean);
#pragma unroll
        for (int k = 0; k < 8; ++k) { float d = yn[k] - mean; var += v[k] * d * d; }
        var /= count;
        float vs = fmaxf(0.6f * var, 2e-6f);
        float inv_vs = 1.f / vs;

        float wk[8], ws = 0.f;
#pragma unroll
        for (int k = 0; k < 8; ++k) {
            float d = yn[k] - yc;
            wk[k] = v[k] * expf(-d * d * inv_vs);
            ws += wk[k];
        }
        if (mask[i * Ww + j]) {
            lo.x = -0.0f;  // sign bit => x_new = x_center (colored pixel frozen)
        } else {
            float scale = 1.f / ws;
            lo = make_float4(wk[0] * scale, wk[1] * scale, wk[2] * scale, wk[3] * scale);
            hi = make_float4(wk[4] * scale, wk[5] * scale, wk[6] * scale, wk[7] * scale);
        }
    }
    w[2 * p + 0] = lo;
    w[2 * p + 1] = hi;
}

// ---------------------------------------------------------------------------
// iter5 v2: temporal-tiled stencil, register-window edition.
// Each active thread (200 of 256) owns a 2-wide x 4-tall output patch:
//   strip s = tid/20 -> rows r0=1+4s .. r0+3;  cp = tid%20 -> cols c0=1+2cp, c0+1.
// Per sweep it slides a 3-row x 4-col register window down the strip:
//   2 ds_read_b128 per row advance (cols c0-1..c0+2), 8 px computed per
//   3 rows resident, 2 ds_write_b64 per row. 12 b128 reads + 8 b64 writes
//   per sweep vs 80 b64 ops for the same 8 px in the naive form.
// No trapezoid guards: full 40x40 inner region computed every sweep; rim
// values are garbage after sweep 1 but are never read by valid pixels
// (valid set shrinks by exactly 1/side/sweep; final 32x32 tile is valid).
// Weights: 16 float4 in registers, loaded once per launch (as R3).
// ---------------------------------------------------------------------------
__global__ __launch_bounds__(256, 4)
void iter5_kernel(const float2* __restrict__ xin, float2* __restrict__ xout,
                  const float4* __restrict__ w) {
    __shared__ __align__(16) float2 xs[2][R * XS];
    int tid = threadIdx.x;
    int gi0 = blockIdx.y * TILE - T;  // image row of region r=0
    int gj0 = blockIdx.x * TILE - T;

    // stage x region into xs[0]
#pragma unroll
    for (int k = 0; k < NK; ++k) {
        int pidx = tid + k * 256;
        if (pidx < NPX) {
            int r = pidx / R, c = pidx - r * R;
            int gp = (gi0 + r + PO) * PS + (gj0 + c + PO);
            xs[0][r * XS + c] = xin[gp];
        }
    }

    bool active = tid < 200;
    int s  = tid / 20;
    int cp = tid - s * 20;
    int r0 = 1 + 4 * s;        // output rows r0..r0+3 (in [1,40])
    int c0 = 1 + 2 * cp;       // output cols c0, c0+1 (odd base => aligned reads)

    // weights for the 8 patch pixels, resident all 5 sweeps
    float4 wl[4], wh[4], vl[4], vh[4];
    if (active) {
#pragma unroll
        for (int i = 0; i < 4; ++i) {
            int gp = (gi0 + r0 + i + PO) * PS + (gj0 + c0 + PO);
            wl[i] = w[2 * gp + 0];
            wh[i] = w[2 * gp + 1];
            vl[i] = w[2 * gp + 2];   // pixel (r0+i, c0+1)
            vh[i] = w[2 * gp + 3];
        }
    }
    __syncthreads();

    int cur = 0;
#pragma unroll
    for (int t = 1; t <= T; ++t) {
        int nxt = cur ^ 1;
        if (active) {
            const float4* pu = (const float4*)&xs[cur][(r0 - 1) * XS + (c0 - 1)];
            float4 ua = pu[0], ub = pu[1];
            const float4* pm = (const float4*)&xs[cur][r0 * XS + (c0 - 1)];
            float4 ma = pm[0], mb = pm[1];
#pragma unroll
            for (int i = 0; i < 4; ++i) {
                const float4* pd = (const float4*)&xs[cur][(r0 + i + 1) * XS + (c0 - 1)];
                float4 da = pd[0], db = pd[1];

                // left pixel (r0+i, c0): cols c0-1,c0,c0+1 -> ua/ub, ma/mb, da/db
                float4 lo = wl[i], hi = wh[i];
                bool keep = (__float_as_uint(lo.x) >> 31) != 0u;
                float ax = keep ? ma.z : 0.f;
                float ay = keep ? ma.w : 0.f;
                ax = fmaf(lo.x, ua.x, ax); ay = fmaf(lo.x, ua.y, ay);  // UL
                ax = fmaf(lo.y, ua.z, ax); ay = fmaf(lo.y, ua.w, ay);  // U
                ax = fmaf(lo.z, ub.x, ax); ay = fmaf(lo.z, ub.y, ay);  // UR
                ax = fmaf(lo.w, ma.x, ax); ay = fmaf(lo.w, ma.y, ay);  // L
                ax = fmaf(hi.x, mb.x, ax); ay = fmaf(hi.x, mb.y, ay);  // R
                ax = fmaf(hi.y, da.x, ax); ay = fmaf(hi.y, da.y, ay);  // DL
                ax = fmaf(hi.z, da.z, ax); ay = fmaf(hi.z, da.w, ay);  // D
                ax = fmaf(hi.w, db.x, ax); ay = fmaf(hi.w, db.y, ay);  // DR

                // right pixel (r0+i, c0+1): cols c0,c0+1,c0+2
                float4 lo2 = vl[i], hi2 = vh[i];
                bool keep2 = (__float_as_uint(lo2.x) >> 31) != 0u;
                float bx = keep2 ? mb.x : 0.f;
                float by = keep2 ? mb.y : 0.f;
                bx = fmaf(lo2.x, ua.z, bx); by = fmaf(lo2.x, ua.w, by);  // UL
                bx = fmaf(lo2.y, ub.x, bx); by = fmaf(lo2.y, ub.y, by);  // U
                bx = fmaf(lo2.z, ub.z, bx); by = fmaf(lo2.z, ub.w, by);  // UR
                bx = fmaf(lo2.w, ma.z, bx); by = fmaf(lo2.w, ma.w, by);  // L
                bx = fmaf(hi2.x, mb.z, bx); by = fmaf(hi2.x, mb.w, by);  // R
                bx = fmaf(hi2.y, da.z, bx); by = fmaf(hi2.y, da.w, by);  // DL
                bx = fmaf(hi2.z, db.x, bx); by = fmaf(hi2.z, db.y, by);  // D
                bx = fmaf(hi2.w, db.z, bx); by = fmaf(hi2.w, db.w, by);  // DR

                int wp = (r0 + i) * XS + c0;
                xs[nxt][wp]     = make_float2(ax, ay);
                xs[nxt][wp + 1] = make_float2(bx, by);

                ua = ma; ub = mb; ma = da; mb = db;  // slide window
            }
        }
        __syncthreads();
        cur = nxt;
    }

    // write central 32x32 tile (region rows/cols 5..36)
#pragma unroll
    for (int k = 0; k < 4; ++k) {
        int pidx = tid + k * 256;
        int r = T + (pidx >> 5), c = T + (pidx & 31);
        int gp = (gi0 + r + PO) * PS + (gj0 + c + PO);
        xout[gp] = xs[cur][r * XS + c];
    }
}

// ---------------------------------------------------------------------------
// final: yiq -> rgb, clip, *255
// ---------------------------------------------------------------------------
__global__ __launch_bounds__(256)
void final_kernel(const float* __restrict__ Ypad, const float2* __restrict__ x,
                  float* __restrict__ out) {
    int j = blockIdx.x * 64 + threadIdx.x;
    int i = blockIdx.y * 4 + threadIdx.y;
    int idx = i * Ww + j;
    int p = (i + PO) * PS + (j + PO);
    float y = Ypad[p];
    float2 iq = x[p];
    float R_ = y + 0.9468822170900693f * iq.x + 0.6235565819861433f * iq.y;
    float G_ = y - 0.27478764629897834f * iq.x - 0.6356910791873801f * iq.y;
    float B_ = y - 1.1085450346420322f * iq.x + 1.7090069284064666f * iq.y;
    out[idx * 3 + 0] = fminf(fmaxf(R_, 0.f), 1.f) * 255.f;
    out[idx * 3 + 1] = fminf(fmaxf(G_, 0.f), 1.f) * 255.f;
    out[idx * 3 + 2] = fminf(fmaxf(B_, 0.f), 1.f) * 255.f;
}

extern "C" void kernel_launch(void* const* d_in, const int* in_sizes, int n_in,
                              void* d_out, int out_size, void* d_ws, size_t ws_size,
                              hipStream_t stream) {
    const float* gray = (const float*)d_in[0];
    const float* app  = (const float*)d_in[1];
    float* out = (float*)d_out;

    char* ws = (char*)d_ws;
    size_t off = 0;
    auto alloc = [&](size_t bytes) -> void* {
        void* r = ws + off;
        off = (off + bytes + 255) & ~(size_t)255;
        return r;
    };
    float*  Ypad = (float*) alloc((size_t)PS * PS * sizeof(float));
    float4* w    = (float4*)alloc((size_t)PS * PS * 8 * sizeof(float));
    unsigned char* mask = (unsigned char*)alloc((size_t)Hh * Ww);
    float2* x0   = (float2*)alloc((size_t)PS * PS * sizeof(float2));
    float2* x1   = (float2*)alloc((size_t)PS * PS * sizeof(float2));

    dim3 blk(64, 4);
    dim3 gridPad((PS + 63) / 64, (PS + 3) / 4);
    prep_kernel<<<gridPad, blk, 0, stream>>>(gray, app, Ypad, x0, x1, mask);
    weights_kernel<<<gridPad, blk, 0, stream>>>(Ypad, mask, w);

    dim3 gridIter(Ww / TILE, Hh / TILE);  // 32 x 32 blocks
    float2* xin = x0;
    float2* xout = x1;
    for (int l = 0; l < 20; ++l) {        // 20 x 5 = 100 iterations
        iter5_kernel<<<gridIter, 256, 0, stream>>>(xin, xout, w);
        float2* tmp = xin; xin = xout; xout = tmp;
    }

    dim3 gridImg(Ww / 64, Hh / 4);
    final_kernel<<<gridImg, blk, 0, stream>>>(Ypad, xin, out);
}

// Round 5
// 353.365 us; speedup vs baseline: 3.1286x; 1.0624x over previous
//
#include <hip/hip_runtime.h>
#include <hip/hip_fp16.h>

#define Hh 1024
#define Ww 1024
#define PS 1040      // padded row stride (image at offset PO)
#define PO 8         // halo offset (>= T+1)
#define T 5          // fused iterations per launch (100 = 20 launches x 5)
#define TILE 32      // output tile per block
#define R 42         // region = TILE + 2T
#define XS 44        // LDS row stride in float2 (EVEN -> 16B-aligned float4 reads)
#define NPX (R * R)  // 1764 region pixels
#define NK 7         // ceil(NPX / 256)

// packed per-pixel weights: 8 x fp16 in one 16B struct (w0..w7)
struct alignas(16) W8 { __half2 a, b, c, d; };

// ---------------------------------------------------------------------------
// prep: Ypad (luma, zero halo), x0 = b (IQ if colored else 0, zero halo),
//       x1 = 0, mask (isColored)
// ---------------------------------------------------------------------------
__global__ __launch_bounds__(256)
void prep_kernel(const float* __restrict__ gray, const float* __restrict__ app,
                 float* __restrict__ Ypad, float2* __restrict__ x0,
                 float2* __restrict__ x1, unsigned char* __restrict__ mask) {
    int px = blockIdx.x * 64 + threadIdx.x;
    int py = blockIdx.y * 4 + threadIdx.y;
    if (px >= PS || py >= PS) return;
    int p = py * PS + px;
    int i = py - PO, j = px - PO;
    float yv = 0.f;
    float2 bv = make_float2(0.f, 0.f);
    if (i >= 0 && i < Hh && j >= 0 && j < Ww) {
        int idx = i * Ww + j;
        const float s = 1.f / 255.f;
        float gr = gray[idx * 3 + 0] * s;
        float gg = gray[idx * 3 + 1] * s;
        float gb = gray[idx * 3 + 2] * s;
        float ar = app[idx * 3 + 0] * s;
        float ag = app[idx * 3 + 1] * s;
        float ab = app[idx * 3 + 2] * s;
        float diff = fabsf(gr - ar) + fabsf(gg - ag) + fabsf(gb - ab);
        bool colored = diff > 0.01f;
        yv = 0.3f * gr + 0.59f * gg + 0.11f * gb;
        float ay = 0.3f * ar + 0.59f * ag + 0.11f * ab;
        float ai = 0.74f * (ar - ay) - 0.27f * (ab - ay);
        float aq = 0.48f * (ar - ay) + 0.41f * (ab - ay);
        if (colored) bv = make_float2(ai, aq);
        mask[idx] = colored ? 1 : 0;
    }
    Ypad[p] = yv;
    x0[p] = bv;
    x1[p] = make_float2(0.f, 0.f);
}

// ---------------------------------------------------------------------------
// weights: per padded pixel, 8 normalized neighbor weights packed fp16 (16B).
// Outside the image: all zero. Colored pixel: all zero except sign bit on w0
// (-0.0h = "keep center").
// ---------------------------------------------------------------------------
__global__ __launch_bounds__(256)
void weights_kernel(const float* __restrict__ Ypad,
                    const unsigned char* __restrict__ mask,
                    W8* __restrict__ w) {
    int px = blockIdx.x * 64 + threadIdx.x;
    int py = blockIdx.y * 4 + threadIdx.y;
    if (px >= PS || py >= PS) return;
    int p = py * PS + px;
    int i = py - PO, j = px - PO;
    W8 out;
    out.a = __floats2half2_rn(0.f, 0.f);
    out.b = out.a; out.c = out.a; out.d = out.a;
    if (i >= 0 && i < Hh && j >= 0 && j < Ww) {
        float yc = Ypad[p];
        float yn[8];
        yn[0] = Ypad[p - PS - 1]; yn[1] = Ypad[p - PS]; yn[2] = Ypad[p - PS + 1];
        yn[3] = Ypad[p - 1];                            yn[4] = Ypad[p + 1];
        yn[5] = Ypad[p + PS - 1]; yn[6] = Ypad[p + PS]; yn[7] = Ypad[p + PS + 1];
        float vt = (i > 0) ? 1.f : 0.f;
        float vb = (i < Hh - 1) ? 1.f : 0.f;
        float vl = (j > 0) ? 1.f : 0.f;
        float vr = (j < Ww - 1) ? 1.f : 0.f;
        float v[8] = { vt * vl, vt, vt * vr, vl, vr, vb * vl, vb, vb * vr };

        float count = 1.f, s1 = yc;
#pragma unroll
        for (int k = 0; k < 8; ++k) { count += v[k]; s1 += v[k] * yn[k]; }
        float mean = s1 / count;
        float var = (yc - mean) * (yc - mean);
#pragma unroll
        for (int k = 0; k < 8; ++k) { float d = yn[k] - mean; var += v[k] * d * d; }
        var /= count;
        float vs = fmaxf(0.6f * var, 2e-6f);
        float inv_vs = 1.f / vs;

        float wk[8], ws = 0.f;
#pragma unroll
        for (int k = 0; k < 8; ++k) {
            float d = yn[k] - yc;
            wk[k] = v[k] * expf(-d * d * inv_vs);
            ws += wk[k];
        }
        if (mask[i * Ww + j]) {
            out.a = __floats2half2_rn(-0.0f, 0.f);  // sign bit => keep center
        } else {
            float scale = 1.f / ws;
            out.a = __floats2half2_rn(wk[0] * scale, wk[1] * scale);
            out.b = __floats2half2_rn(wk[2] * scale, wk[3] * scale);
            out.c = __floats2half2_rn(wk[4] * scale, wk[5] * scale);
            out.d = __floats2half2_rn(wk[6] * scale, wk[7] * scale);
        }
    }
    w[p] = out;
}

// ---------------------------------------------------------------------------
// iter5 v3: temporal-tiled register-window stencil (as R4), but weights are
// loaded as packed fp16 (8 b128 loads/thread instead of 16) and unpacked
// ONCE per launch into f32 registers -> inner loop identical to R4.
// ---------------------------------------------------------------------------
__global__ __launch_bounds__(256, 4)
void iter5_kernel(const float2* __restrict__ xin, float2* __restrict__ xout,
                  const W8* __restrict__ w) {
    __shared__ __align__(16) float2 xs[2][R * XS];
    int tid = threadIdx.x;
    int gi0 = blockIdx.y * TILE - T;  // image row of region r=0
    int gj0 = blockIdx.x * TILE - T;

    // stage x region into xs[0]
#pragma unroll
    for (int k = 0; k < NK; ++k) {
        int pidx = tid + k * 256;
        if (pidx < NPX) {
            int r = pidx / R, c = pidx - r * R;
            int gp = (gi0 + r + PO) * PS + (gj0 + c + PO);
            xs[0][r * XS + c] = xin[gp];
        }
    }

    bool active = tid < 200;
    int s  = tid / 20;
    int cp = tid - s * 20;
    int r0 = 1 + 4 * s;        // output rows r0..r0+3 (in [1,40])
    int c0 = 1 + 2 * cp;       // output cols c0, c0+1

    // packed weight loads (8 x b128), unpacked once to f32 for all 5 sweeps
    float4 wl[4], wh[4], vl[4], vh[4];
    if (active) {
#pragma unroll
        for (int i = 0; i < 4; ++i) {
            int gp = (gi0 + r0 + i + PO) * PS + (gj0 + c0 + PO);
            W8 wa = w[gp];
            W8 wb = w[gp + 1];
            float2 a0 = __half22float2(wa.a), a1 = __half22float2(wa.b);
            float2 a2 = __half22float2(wa.c), a3 = __half22float2(wa.d);
            float2 b0 = __half22float2(wb.a), b1 = __half22float2(wb.b);
            float2 b2 = __half22float2(wb.c), b3 = __half22float2(wb.d);
            wl[i] = make_float4(a0.x, a0.y, a1.x, a1.y);
            wh[i] = make_float4(a2.x, a2.y, a3.x, a3.y);
            vl[i] = make_float4(b0.x, b0.y, b1.x, b1.y);
            vh[i] = make_float4(b2.x, b2.y, b3.x, b3.y);
        }
    }
    __syncthreads();

    int cur = 0;
#pragma unroll
    for (int t = 1; t <= T; ++t) {
        int nxt = cur ^ 1;
        if (active) {
            const float4* pu = (const float4*)&xs[cur][(r0 - 1) * XS + (c0 - 1)];
            float4 ua = pu[0], ub = pu[1];
            const float4* pm = (const float4*)&xs[cur][r0 * XS + (c0 - 1)];
            float4 ma = pm[0], mb = pm[1];
#pragma unroll
            for (int i = 0; i < 4; ++i) {
                const float4* pd = (const float4*)&xs[cur][(r0 + i + 1) * XS + (c0 - 1)];
                float4 da = pd[0], db = pd[1];

                // left pixel (r0+i, c0)
                float4 lo = wl[i], hi = wh[i];
                bool keep = (__float_as_uint(lo.x) >> 31) != 0u;
                float ax = keep ? ma.z : 0.f;
                float ay = keep ? ma.w : 0.f;
                ax = fmaf(lo.x, ua.x, ax); ay = fmaf(lo.x, ua.y, ay);  // UL
                ax = fmaf(lo.y, ua.z, ax); ay = fmaf(lo.y, ua.w, ay);  // U
                ax = fmaf(lo.z, ub.x, ax); ay = fmaf(lo.z, ub.y, ay);  // UR
                ax = fmaf(lo.w, ma.x, ax); ay = fmaf(lo.w, ma.y, ay);  // L
                ax = fmaf(hi.x, mb.x, ax); ay = fmaf(hi.x, mb.y, ay);  // R
                ax = fmaf(hi.y, da.x, ax); ay = fmaf(hi.y, da.y, ay);  // DL
                ax = fmaf(hi.z, da.z, ax); ay = fmaf(hi.z, da.w, ay);  // D
                ax = fmaf(hi.w, db.x, ax); ay = fmaf(hi.w, db.y, ay);  // DR

                // right pixel (r0+i, c0+1)
                float4 lo2 = vl[i], hi2 = vh[i];
                bool keep2 = (__float_as_uint(lo2.x) >> 31) != 0u;
                float bx = keep2 ? mb.x : 0.f;
                float by = keep2 ? mb.y : 0.f;
                bx = fmaf(lo2.x, ua.z, bx); by = fmaf(lo2.x, ua.w, by);  // UL
                bx = fmaf(lo2.y, ub.x, bx); by = fmaf(lo2.y, ub.y, by);  // U
                bx = fmaf(lo2.z, ub.z, bx); by = fmaf(lo2.z, ub.w, by);  // UR
                bx = fmaf(lo2.w, ma.z, bx); by = fmaf(lo2.w, ma.w, by);  // L
                bx = fmaf(hi2.x, mb.z, bx); by = fmaf(hi2.x, mb.w, by);  // R
                bx = fmaf(hi2.y, da.z, bx); by = fmaf(hi2.y, da.w, by);  // DL
                bx = fmaf(hi2.z, db.x, bx); by = fmaf(hi2.z, db.y, by);  // D
                bx = fmaf(hi2.w, db.z, bx); by = fmaf(hi2.w, db.w, by);  // DR

                int wp = (r0 + i) * XS + c0;
                xs[nxt][wp]     = make_float2(ax, ay);
                xs[nxt][wp + 1] = make_float2(bx, by);

                ua = ma; ub = mb; ma = da; mb = db;  // slide window
            }
        }
        __syncthreads();
        cur = nxt;
    }

    // write central 32x32 tile (region rows/cols 5..36)
#pragma unroll
    for (int k = 0; k < 4; ++k) {
        int pidx = tid + k * 256;
        int r = T + (pidx >> 5), c = T + (pidx & 31);
        int gp = (gi0 + r + PO) * PS + (gj0 + c + PO);
        xout[gp] = xs[cur][r * XS + c];
    }
}

// ---------------------------------------------------------------------------
// final: yiq -> rgb, clip, *255
// ---------------------------------------------------------------------------
__global__ __launch_bounds__(256)
void final_kernel(const float* __restrict__ Ypad, const float2* __restrict__ x,
                  float* __restrict__ out) {
    int j = blockIdx.x * 64 + threadIdx.x;
    int i = blockIdx.y * 4 + threadIdx.y;
    int idx = i * Ww + j;
    int p = (i + PO) * PS + (j + PO);
    float y = Ypad[p];
    float2 iq = x[p];
    float R_ = y + 0.9468822170900693f * iq.x + 0.6235565819861433f * iq.y;
    float G_ = y - 0.27478764629897834f * iq.x - 0.6356910791873801f * iq.y;
    float B_ = y - 1.1085450346420322f * iq.x + 1.7090069284064666f * iq.y;
    out[idx * 3 + 0] = fminf(fmaxf(R_, 0.f), 1.f) * 255.f;
    out[idx * 3 + 1] = fminf(fmaxf(G_, 0.f), 1.f) * 255.f;
    out[idx * 3 + 2] = fminf(fmaxf(B_, 0.f), 1.f) * 255.f;
}

extern "C" void kernel_launch(void* const* d_in, const int* in_sizes, int n_in,
                              void* d_out, int out_size, void* d_ws, size_t ws_size,
                              hipStream_t stream) {
    const float* gray = (const float*)d_in[0];
    const float* app  = (const float*)d_in[1];
    float* out = (float*)d_out;

    char* ws = (char*)d_ws;
    size_t off = 0;
    auto alloc = [&](size_t bytes) -> void* {
        void* r = ws + off;
        off = (off + bytes + 255) & ~(size_t)255;
        return r;
    };
    float*  Ypad = (float*) alloc((size_t)PS * PS * sizeof(float));
    W8*     w    = (W8*)    alloc((size_t)PS * PS * sizeof(W8));
    unsigned char* mask = (unsigned char*)alloc((size_t)Hh * Ww);
    float2* x0   = (float2*)alloc((size_t)PS * PS * sizeof(float2));
    float2* x1   = (float2*)alloc((size_t)PS * PS * sizeof(float2));

    dim3 blk(64, 4);
    dim3 gridPad((PS + 63) / 64, (PS + 3) / 4);
    prep_kernel<<<gridPad, blk, 0, stream>>>(gray, app, Ypad, x0, x1, mask);
    weights_kernel<<<gridPad, blk, 0, stream>>>(Ypad, mask, w);

    dim3 gridIter(Ww / TILE, Hh / TILE);  // 32 x 32 blocks
    float2* xin = x0;
    float2* xout = x1;
    for (int l = 0; l < 20; ++l) {        // 20 x 5 = 100 iterations
        iter5_kernel<<<gridIter, 256, 0, stream>>>(xin, xout, w);
        float2* tmp = xin; xin = xout; xout = tmp;
    }

    dim3 gridImg(Ww / 64, Hh / 4);
    final_kernel<<<gridImg, blk, 0, stream>>>(Ypad, xin, out);
}